// Round 2
// baseline (206.454 us; speedup 1.0000x reference)
//
#include <hip/hip_runtime.h>
#include <math.h>

#define NPATCH 128
#define CH 8            // channels per patch = L / N_PATCHES
#define D 64
#define WIN 9           // key patches ahead (diff in 1..9)
#define MAXK (WIN*CH)   // 72

__global__ __launch_bounds__(256, 4) void signed_attn_kernel(
    const float* __restrict__ Q, const float* __restrict__ K,
    const float* __restrict__ V, const float* __restrict__ logscale,
    float* __restrict__ O)
{
    // K/V tiles, float4-granular, XOR-swizzled columns: (k,d4) stored at col d4^(k&15)
    __shared__ float4 sK4[MAXK * 16];          // 18432 B
    __shared__ float4 sV4[MAXK * 16];          // 18432 B
    __shared__ float4 sQA[CH * (MAXK / 4)];    // 2304 B: Q tile (first 128 f4), then A matrix
    float* fA = (float*)sQA;
    // total 39168 B -> 4 blocks/CU

    const int tid = threadIdx.x;
    const int bid = blockIdx.x;
    const int p   = bid & (NPATCH - 1);
    const int bh  = bid >> 7;

    const long long base  = (long long)bh * (NPATCH * CH) * D;
    const long long qbase = base + (long long)(p * CH) * D;
    float4* Og4 = (float4*)(O + qbase);

    const int npk = min(WIN, NPATCH - 1 - p);
    const int nk  = npk * CH;                  // multiple of 8 (or 0)

    if (nk == 0) {                             // patch 127: fully masked -> A==0 exactly
        if (tid < CH * D / 4) Og4[tid] = make_float4(0.f, 0.f, 0.f, 0.f);
        return;
    }

    const float scale = fminf(fmaxf(__expf(logscale[0]), 1.0f), 30.0f) * 0.125f;

    // ---- stage Q + K + V (all float4) ----
    {
        const float4* Qg = (const float4*)(Q + qbase);
        if (tid < CH * D / 4) sQA[tid] = Qg[tid];
        const long long kbase = base + (long long)((p + 1) * CH) * D;
        const float4* Kg = (const float4*)(K + kbase);
        const float4* Vg = (const float4*)(V + kbase);
        const int n4 = nk * 16;
        for (int i = tid; i < n4; i += 256) {
            const int k = i >> 4, d4 = i & 15, c = d4 ^ (k & 15);
            sK4[k * 16 + c] = Kg[i];
            sV4[k * 16 + c] = Vg[i];
        }
    }
    __syncthreads();

    // ---- scores in registers: wave w owns rows q0=2w,q0+1; lane kg owns keys kg (+ 64+kg if kg<8)
    const int w  = tid >> 6;
    const int kg = tid & 63;
    const int q0 = 2 * w, q1 = 2 * w + 1;
    const bool hasK1 = (kg < MAXK - 64);       // kg < 8
    const int k1 = 64 + kg;

    float a00 = 0.f, a01 = 0.f, a10 = 0.f, a11 = 0.f;
#pragma unroll
    for (int d4 = 0; d4 < 16; ++d4) {
        const float4 qa = sQA[q0 * 16 + d4];   // broadcast
        const float4 qb = sQA[q1 * 16 + d4];   // broadcast
        const float4 ka = sK4[kg * 16 + (d4 ^ (kg & 15))];
        a00 += qa.x * ka.x + qa.y * ka.y + qa.z * ka.z + qa.w * ka.w;
        a10 += qb.x * ka.x + qb.y * ka.y + qb.z * ka.z + qb.w * ka.w;
        if (hasK1) {
            const float4 kb = sK4[k1 * 16 + (d4 ^ (k1 & 15))];
            a01 += qa.x * kb.x + qa.y * kb.y + qa.z * kb.z + qa.w * kb.w;
            a11 += qb.x * kb.x + qb.y * kb.y + qb.z * kb.z + qb.w * kb.w;
        }
    }

    // ---- dual softmax, all in registers (wave-wide shuffles) ----
    const bool v0 = (kg < nk);
    const bool v1 = hasK1 && (k1 < nk);
    const float t00 = scale * a00, t01 = scale * a01;
    const float t10 = scale * a10, t11 = scale * a11;

    float mp0 = fmaxf(v0 ? t00 : -1e30f, v1 ? t01 : -1e30f);
    float mn0 = fmaxf(v0 ? -t00 : -1e30f, v1 ? -t01 : -1e30f);
    float mp1 = fmaxf(v0 ? t10 : -1e30f, v1 ? t11 : -1e30f);
    float mn1 = fmaxf(v0 ? -t10 : -1e30f, v1 ? -t11 : -1e30f);
#pragma unroll
    for (int off = 32; off > 0; off >>= 1) {
        mp0 = fmaxf(mp0, __shfl_xor(mp0, off));
        mn0 = fmaxf(mn0, __shfl_xor(mn0, off));
        mp1 = fmaxf(mp1, __shfl_xor(mp1, off));
        mn1 = fmaxf(mn1, __shfl_xor(mn1, off));
    }

    const float ep00 = v0 ? __expf(t00 - mp0) : 0.f;
    const float en00 = v0 ? __expf(-t00 - mn0) : 0.f;
    const float ep01 = v1 ? __expf(t01 - mp0) : 0.f;
    const float en01 = v1 ? __expf(-t01 - mn0) : 0.f;
    const float ep10 = v0 ? __expf(t10 - mp1) : 0.f;
    const float en10 = v0 ? __expf(-t10 - mn1) : 0.f;
    const float ep11 = v1 ? __expf(t11 - mp1) : 0.f;
    const float en11 = v1 ? __expf(-t11 - mn1) : 0.f;

    float sp0 = ep00 + ep01, sn0 = en00 + en01;
    float sp1 = ep10 + ep11, sn1 = en10 + en11;
#pragma unroll
    for (int off = 32; off > 0; off >>= 1) {
        sp0 += __shfl_xor(sp0, off);
        sn0 += __shfl_xor(sn0, off);
        sp1 += __shfl_xor(sp1, off);
        sn1 += __shfl_xor(sn1, off);
    }
    const float rp0 = 1.f / sp0, rn0 = 1.f / sn0;
    const float rp1 = 1.f / sp1, rn1 = 1.f / sn1;

    const float A00 = ep00 * rp0 - en00 * rn0;
    const float A01 = ep01 * rp0 - en01 * rn0;
    const float A10 = ep10 * rp1 - en10 * rn1;
    const float A11 = ep11 * rp1 - en11 * rn1;

    __syncthreads();   // everyone done reading Q tile; sQA becomes A
    fA[q0 * MAXK + kg] = A00;                      // invalid keys write exact 0
    fA[q1 * MAXK + kg] = A10;
    if (hasK1) {
        fA[q0 * MAXK + k1] = A01;
        fA[q1 * MAXK + k1] = A11;
    }
    __syncthreads();

    // ---- O = A * V : thread = (q, half, d4); float4 accumulator over half the keys ----
    const int q    = tid >> 5;
    const int rem  = tid & 31;
    const int half = rem >> 4;
    const int d4   = rem & 15;
    const int nk4  = nk >> 2;

    float4 acc = make_float4(0.f, 0.f, 0.f, 0.f);
    const int kend = min((half + 1) * 9, nk4);
    for (int k4 = half * 9; k4 < kend; ++k4) {
        const float4 a4 = *(const float4*)&fA[q * MAXK + k4 * 4];
        const int kb = k4 * 4;
        const float4 w0 = sV4[(kb + 0) * 16 + (d4 ^ ((kb + 0) & 15))];
        const float4 w1 = sV4[(kb + 1) * 16 + (d4 ^ ((kb + 1) & 15))];
        const float4 w2 = sV4[(kb + 2) * 16 + (d4 ^ ((kb + 2) & 15))];
        const float4 w3 = sV4[(kb + 3) * 16 + (d4 ^ ((kb + 3) & 15))];
        acc.x += a4.x * w0.x + a4.y * w1.x + a4.z * w2.x + a4.w * w3.x;
        acc.y += a4.x * w0.y + a4.y * w1.y + a4.z * w2.y + a4.w * w3.y;
        acc.z += a4.x * w0.z + a4.y * w1.z + a4.z * w2.z + a4.w * w3.z;
        acc.w += a4.x * w0.w + a4.y * w1.w + a4.z * w2.w + a4.w * w3.w;
    }
    acc.x += __shfl_xor(acc.x, 16, 32);
    acc.y += __shfl_xor(acc.y, 16, 32);
    acc.z += __shfl_xor(acc.z, 16, 32);
    acc.w += __shfl_xor(acc.w, 16, 32);
    if (half == 0) Og4[q * 16 + d4] = acc;
}

extern "C" void kernel_launch(void* const* d_in, const int* in_sizes, int n_in,
                              void* d_out, int out_size, void* d_ws, size_t ws_size,
                              hipStream_t stream) {
    const float* Q  = (const float*)d_in[0];
    const float* K  = (const float*)d_in[1];
    const float* V  = (const float*)d_in[2];
    const float* ls = (const float*)d_in[3];
    float* O = (float*)d_out;

    const int L = 1024;
    const int nBH = in_sizes[0] / (L * D);     // B*H = 32
    dim3 grid(nBH * NPATCH);                   // 4096 blocks
    signed_attn_kernel<<<grid, 256, 0, stream>>>(Q, K, V, ls, O);
}

// Round 3
// 103.625 us; speedup vs baseline: 1.9923x; 1.9923x over previous
//
#include <hip/hip_runtime.h>
#include <math.h>

#define NPATCH 128
#define CH 8             // channels per patch = L / N_PATCHES
#define D 64
#define WIN 9            // key patches ahead (diff in 1..9)
#define MAXK (WIN*CH)    // 72
#define KT_STRIDE 73     // float4 units; odd => per-row bank rotation

__global__ __launch_bounds__(256) void signed_attn_kernel(
    const float* __restrict__ Q, const float* __restrict__ K,
    const float* __restrict__ V, const float* __restrict__ logscale,
    float* __restrict__ O)
{
    __shared__ float4 sKT[16 * KT_STRIDE];        // K^T by f4: (d4,k) at d4*73+k ; 18688 B
    __shared__ float4 sV4[MAXK * 16];             // V row-major (k,d4)          ; 18432 B
    __shared__ __align__(16) float fA[CH][MAXK];  // A matrix                    ;  2304 B
    // total 39424 B -> 4 blocks/CU

    const int tid = threadIdx.x;
    const int bid = blockIdx.x;
    const int p   = bid & (NPATCH - 1);
    const int bh  = bid >> 7;

    const long long base  = (long long)bh * (NPATCH * CH) * D;
    const long long qbase = base + (long long)(p * CH) * D;
    float4*       Og4 = (float4*)(O + qbase);
    const float4* Qg4 = (const float4*)(Q + qbase);

    const int npk = min(WIN, NPATCH - 1 - p);
    const int nk  = npk * CH;                     // multiple of 8, or 0

    if (nk == 0) {                                // patch 127: fully masked -> A==0 exactly
        if (tid < CH * D / 4) Og4[tid] = make_float4(0.f, 0.f, 0.f, 0.f);
        return;
    }

    const float scale = fminf(fmaxf(__expf(logscale[0]), 1.0f), 30.0f) * 0.125f;

    // ---- stage K (f4-transposed) and V (row-major f4) ----
    {
        const long long kbase = base + (long long)((p + 1) * CH) * D;
        const float4* Kg = (const float4*)(K + kbase);
        const float4* Vg = (const float4*)(V + kbase);
        const int n4 = nk * 16;
        for (int i = tid; i < n4; i += 256) {
            const int k = i >> 4, d4 = i & 15;
            sKT[d4 * KT_STRIDE + k] = Kg[i];
            sV4[i] = Vg[i];
        }
    }
    __syncthreads();

    // ---- scores: half-wave owns q = tid>>5; lane owns keys {lane, lane+32, lane+64(<8)} ----
    const int q    = tid >> 5;
    const int lane = tid & 31;
    const int k2   = (lane < MAXK - 64) ? (64 + lane) : lane;   // dummy alias for lane>=8

    float c0 = 0.f, c1 = 0.f, c2 = 0.f;
#pragma unroll 4
    for (int d4 = 0; d4 < 16; ++d4) {
        const float4 qv  = Qg4[q * 16 + d4];                    // L1-resident broadcast
        const float4 k0v = sKT[d4 * KT_STRIDE + lane];
        const float4 k1v = sKT[d4 * KT_STRIDE + lane + 32];
        const float4 k2v = sKT[d4 * KT_STRIDE + k2];
        c0 += qv.x * k0v.x + qv.y * k0v.y + qv.z * k0v.z + qv.w * k0v.w;
        c1 += qv.x * k1v.x + qv.y * k1v.y + qv.z * k1v.z + qv.w * k1v.w;
        c2 += qv.x * k2v.x + qv.y * k2v.y + qv.z * k2v.z + qv.w * k2v.w;
    }

    // ---- dual softmax, registers + width-32 shuffle butterflies ----
    const bool v0 = (lane      < nk);
    const bool v1 = (lane + 32 < nk);
    const bool v2 = (lane < 8) && (lane + 64 < nk);
    const float t0 = scale * c0, t1 = scale * c1, t2 = scale * c2;

    float mp = fmaxf(fmaxf(v0 ?  t0 : -1e30f, v1 ?  t1 : -1e30f), v2 ?  t2 : -1e30f);
    float mn = fmaxf(fmaxf(v0 ? -t0 : -1e30f, v1 ? -t1 : -1e30f), v2 ? -t2 : -1e30f);
#pragma unroll
    for (int off = 16; off > 0; off >>= 1) {
        mp = fmaxf(mp, __shfl_xor(mp, off, 32));
        mn = fmaxf(mn, __shfl_xor(mn, off, 32));
    }

    const float ep0 = v0 ? __expf( t0 - mp) : 0.f;
    const float en0 = v0 ? __expf(-t0 - mn) : 0.f;
    const float ep1 = v1 ? __expf( t1 - mp) : 0.f;
    const float en1 = v1 ? __expf(-t1 - mn) : 0.f;
    const float ep2 = v2 ? __expf( t2 - mp) : 0.f;
    const float en2 = v2 ? __expf(-t2 - mn) : 0.f;

    float sp = ep0 + ep1 + ep2;
    float sn = en0 + en1 + en2;
#pragma unroll
    for (int off = 16; off > 0; off >>= 1) {
        sp += __shfl_xor(sp, off, 32);
        sn += __shfl_xor(sn, off, 32);
    }
    const float rp = 1.f / sp, rn = 1.f / sn;

    fA[q][lane]      = ep0 * rp - en0 * rn;       // invalid keys get exact 0
    fA[q][lane + 32] = ep1 * rp - en1 * rn;
    if (lane < 8) fA[q][lane + 64] = ep2 * rp - en2 * rn;
    __syncthreads();

    // ---- O = A * V : thread = (q2, half, d4); float4 accumulator over half the keys ----
    const int q2   = tid >> 5;
    const int rem  = tid & 31;
    const int half = rem >> 4;
    const int d4   = rem & 15;
    const int nk4  = nk >> 2;
    const int kst  = half * 9;
    const int kend = min(kst + 9, nk4);

    float4 acc = make_float4(0.f, 0.f, 0.f, 0.f);
    for (int k4 = kst; k4 < kend; ++k4) {
        const float4 a4 = *(const float4*)&fA[q2][k4 * 4];
        const int kb = k4 * 4;
        const float4 w0 = sV4[(kb + 0) * 16 + d4];
        const float4 w1 = sV4[(kb + 1) * 16 + d4];
        const float4 w2 = sV4[(kb + 2) * 16 + d4];
        const float4 w3 = sV4[(kb + 3) * 16 + d4];
        acc.x += a4.x * w0.x + a4.y * w1.x + a4.z * w2.x + a4.w * w3.x;
        acc.y += a4.x * w0.y + a4.y * w1.y + a4.z * w2.y + a4.w * w3.y;
        acc.z += a4.x * w0.z + a4.y * w1.z + a4.z * w2.z + a4.w * w3.z;
        acc.w += a4.x * w0.w + a4.y * w1.w + a4.z * w2.w + a4.w * w3.w;
    }
    acc.x += __shfl_xor(acc.x, 16, 32);
    acc.y += __shfl_xor(acc.y, 16, 32);
    acc.z += __shfl_xor(acc.z, 16, 32);
    acc.w += __shfl_xor(acc.w, 16, 32);
    if (half == 0) Og4[q2 * 16 + d4] = acc;
}

extern "C" void kernel_launch(void* const* d_in, const int* in_sizes, int n_in,
                              void* d_out, int out_size, void* d_ws, size_t ws_size,
                              hipStream_t stream) {
    const float* Q  = (const float*)d_in[0];
    const float* K  = (const float*)d_in[1];
    const float* V  = (const float*)d_in[2];
    const float* ls = (const float*)d_in[3];
    float* O = (float*)d_out;

    const int L = 1024;
    const int nBH = in_sizes[0] / (L * D);        // B*H = 32
    dim3 grid(nBH * NPATCH);                      // 4096 blocks
    signed_attn_kernel<<<grid, 256, 0, stream>>>(Q, K, V, ls, O);
}